// Round 18
// baseline (918.975 us; speedup 1.0000x reference)
//
#include <hip/hip_runtime.h>

// ---------------------------------------------------------------------------
// SpectralNet loss pipeline on MI355X.
//   pass1: y1 = MLP(x1)/d1 -> gram -> cholesky -> operator = inv(L)^T*sqrt(N)
//   pass2: y  = (MLP(x2) @ operator)/d2 -> loss = sum_e de*(d2[i]+d2[j])/N
// GEMM (r18 = r14 schedule + addressing diet): 256x256 tile, BK=64, 512 thr,
// dbuf LDS, early-publish software pipeline (best measured structure).
// NEW r18: KD templated (NT constexpr), K-loop unroll 2 (slot bases become
// constants), per-thread global pointers hoisted + advanced by 64/tile
// (removes in-loop 64-bit address muls; VALUBusy was 25% and serializing
// with MFMA+LDS). Operator folded into pass-2 layer4 (r17 win).
// Degree: atomic-free 3-stage. Cholesky: parallel fp64.
// ---------------------------------------------------------------------------

#define NPTS  65536
#define KNN   16
#define INDIM 128
#define HID   1024
#define HID2  512
#define ODIM  32
#define ESL   32          // edge slices for degree scatter

typedef unsigned short u16;
typedef unsigned int   u32;
typedef __attribute__((ext_vector_type(8))) short bf16x8;
typedef __attribute__((ext_vector_type(4))) float f32x4;

__device__ __forceinline__ u16 f2bf(float v) {
    union { float f; unsigned u; } x; x.f = v;
    unsigned r = x.u + 0x7fffu + ((x.u >> 16) & 1u);   // round-to-nearest-even
    return (u16)(r >> 16);
}

__device__ __forceinline__ void gload_lds16(const u16* g, u16* l) {
    __builtin_amdgcn_global_load_lds(
        (const __attribute__((address_space(1))) u32*)g,
        (__attribute__((address_space(3))) u32*)l, 16, 0, 0);
}

template <int N> __device__ __forceinline__ void vmwait() {
    asm volatile("s_waitcnt vmcnt(%0)" :: "n"(N) : "memory");
}
__device__ __forceinline__ void wg_barrier() {
    asm volatile("s_barrier" ::: "memory");
}

// ---------------- conversion / transpose ----------------
__global__ void cvt_bf16_k(const float* __restrict__ in, u16* __restrict__ out, int n4) {
    int i = blockIdx.x * blockDim.x + threadIdx.x;
    if (i >= n4) return;
    float4 v = reinterpret_cast<const float4*>(in)[i];
    unsigned lo = (unsigned)f2bf(v.x) | ((unsigned)f2bf(v.y) << 16);
    unsigned hi = (unsigned)f2bf(v.z) | ((unsigned)f2bf(v.w) << 16);
    reinterpret_cast<uint2*>(out)[i] = make_uint2(lo, hi);
}

// W [rows][cols] f32 -> Wt [cols][rows] bf16   (write-coalesced)
__global__ void trans_bf16_k(const float* __restrict__ W, u16* __restrict__ Wt,
                             int rows, int cols) {
    int idx = blockIdx.x * blockDim.x + threadIdx.x;
    if (idx >= rows * cols) return;
    int o = idx / rows, i = idx - o * rows;
    Wt[idx] = f2bf(W[(size_t)i * cols + o]);
}

// ---- fold operator into layer 4:  W4t'[o][h] = sum_j W4[h][j] O[j][o],
//      b4f[o] = sum_j b4[j] O[j][o].  (O = oper, row-major [32][32])
__global__ void oper_fold_k(const float* __restrict__ W4, const float* __restrict__ b4,
                            const float* __restrict__ oper,
                            u16* __restrict__ W4tP, float* __restrict__ b4f) {
    __shared__ float op[1024];
    int tid = threadIdx.x;
    #pragma unroll
    for (int j = tid; j < 1024; j += 256) op[j] = oper[j];
    __syncthreads();
    int idx = blockIdx.x * 256 + tid;              // 0 .. 512*32+32-1
    if (idx < HID2 * ODIM) {
        int o = idx & 31, h = idx >> 5;
        float s = 0.f;
        #pragma unroll
        for (int j = 0; j < 32; ++j) s += W4[h * 32 + j] * op[j * 32 + o];
        W4tP[o * HID2 + h] = f2bf(s);
    } else if (idx < HID2 * ODIM + ODIM) {
        int o = idx - HID2 * ODIM;
        float s = 0.f;
        #pragma unroll
        for (int j = 0; j < 32; ++j) s += b4[j] * op[j * 32 + o];
        b4f[o] = s;
    }
}

// ---------------- degree stage 1: edge weights + row half ----------------
__global__ void edgew_k(const float* __restrict__ dists1, float* __restrict__ w1,
                        float* __restrict__ dr1,
                        const float* __restrict__ dists2, float* __restrict__ w2,
                        float* __restrict__ dr2) {
    const float* dists = blockIdx.y ? dists2 : dists1;
    float*       wbuf  = blockIdx.y ? w2     : w1;
    float*       drow  = blockIdx.y ? dr2    : dr1;
    int i = blockIdx.x * blockDim.x + threadIdx.x;
    if (i >= NPTS) return;
    const float4* dr = reinterpret_cast<const float4*>(dists + (size_t)i * KNN);
    float4 a = dr[0], b = dr[1], c = dr[2], e = dr[3];
    float buf[KNN] = {a.x,a.y,a.z,a.w,b.x,b.y,b.z,b.w,c.x,c.y,c.z,c.w,e.x,e.y,e.z,e.w};
    float s = 0.f;
    #pragma unroll
    for (int k = 0; k < KNN; ++k) s += buf[k];
    float sigma = s * (1.f / KNN);
    float inv2s2 = 1.f / (2.f * sigma * sigma);
    float w[KNN];
    float rs = 0.f;
    #pragma unroll
    for (int k = 0; k < KNN; ++k) { w[k] = __expf(-buf[k] * buf[k] * inv2s2); rs += w[k]; }
    drow[i] = 0.5f * rs;
    float4* wo = reinterpret_cast<float4*>(wbuf + (size_t)i * KNN);
    wo[0] = make_float4(w[0], w[1], w[2], w[3]);
    wo[1] = make_float4(w[4], w[5], w[6], w[7]);
    wo[2] = make_float4(w[8], w[9], w[10], w[11]);
    wo[3] = make_float4(w[12], w[13], w[14], w[15]);
}

// ---------------- degree stage 2: LDS-binned scatter into partials ----------
__global__ __launch_bounds__(512) void scatter_k(
    const int* __restrict__ nn1, const float* __restrict__ w1,
    const int* __restrict__ nn2, const float* __restrict__ w2,
    float* __restrict__ partial) {
    __shared__ float bins[16384];
    const int slice = blockIdx.x, range = blockIdx.y, g = blockIdx.z;
    const int* nn   = g ? nn2 : nn1;
    const float* wb = g ? w2  : w1;
    for (int b = threadIdx.x; b < 16384; b += 512) bins[b] = 0.f;
    __syncthreads();
    const int per4  = (NPTS * KNN / ESL) >> 2;       // 8192 int4 per slice
    const int base4 = slice * per4;
    const int4*   nn4 = reinterpret_cast<const int4*>(nn);
    const float4* w4  = reinterpret_cast<const float4*>(wb);
    #pragma unroll 2
    for (int k = 0; k < per4 / 512; ++k) {           // 16 iterations
        int e4 = base4 + k * 512 + threadIdx.x;
        int4   idx = nn4[e4];
        float4 wv  = w4[e4];
        if ((idx.x >> 14) == range) atomicAdd(&bins[idx.x & 16383], wv.x);
        if ((idx.y >> 14) == range) atomicAdd(&bins[idx.y & 16383], wv.y);
        if ((idx.z >> 14) == range) atomicAdd(&bins[idx.z & 16383], wv.z);
        if ((idx.w >> 14) == range) atomicAdd(&bins[idx.w & 16383], wv.w);
    }
    __syncthreads();
    float* dst = partial + ((size_t)(g * ESL + slice) << 16) + (range << 14);
    for (int b = threadIdx.x; b < 16384; b += 512) dst[b] = bins[b];
}

// ---------------- degree stage 3: d[i] = rowhalf + 0.5*sum_slices -----------
__global__ __launch_bounds__(256) void dreduce_k(
    const float* __restrict__ partial, float* __restrict__ d1, float* __restrict__ d2) {
    int i = blockIdx.x * 256 + threadIdx.x;      // 0..65535
    int g = blockIdx.y;
    const float* p = partial + ((size_t)(g * ESL) << 16) + i;
    float s = 0.f;
    #pragma unroll 8
    for (int sl = 0; sl < ESL; ++sl) s += p[(size_t)sl << 16];
    float* d = g ? d2 : d1;
    d[i] += 0.5f * s;
}

// ---------------- GEMM: C = relu(A @ Bt^T + bias), bf16 in/out --------------
// BM=256, BN=256, BK=64, 512 threads = 8 waves (2 M x 4 N), per-wave 128x64.
// r14 early-publish pipeline + constexpr NT, unroll-2 K-loop, hoisted global
// pointers (advanced +64/tile) to cut in-loop VALU address work.
template <bool RELU, int KD>
__global__ __launch_bounds__(512) void gemm256_k(
    const u16* __restrict__ A, const u16* __restrict__ Bt,
    const float* __restrict__ bias, u16* __restrict__ C,
    int M, int Ncols)
{
    constexpr int BN   = 256;
    constexpr int AL   = 4;                // A gload_lds per thread per K-tile
    constexpr int BL   = 4;                // B gload_lds per thread per K-tile
    constexpr int NT   = KD >> 6;          // K-tiles (2 or 16)
    constexpr int A_U16  = 2 * 256 * 64;            // dbuf A
    constexpr int B_U16  = 2 * BN * 64;             // dbuf B
    constexpr int LDSC   = BN + 16;                 // epilogue row stride (u16)
    constexpr int EP_U16 = 256 * LDSC;
    constexpr int SM_U16 = (A_U16 + B_U16 > EP_U16) ? (A_U16 + B_U16) : EP_U16;

    __shared__ __attribute__((aligned(16))) u16 smem[SM_U16];
    u16* Asm = smem;                 // [2][256*64]
    u16* Bsm = smem + A_U16;         // [2][BN*64]

    const int tid  = threadIdx.x;
    const int lane = tid & 63;
    const int wave = tid >> 6;       // 0..7
    const int wr   = wave >> 2;      // 0..1
    const int wc   = wave & 3;       // 0..3
    const int l15  = lane & 15;
    const int kq   = lane >> 4;      // 0..3

    // bijective XCD-chunked swizzle of the linear block id (T1/m204)
    const int nwg = gridDim.x * gridDim.y;
    int sid = blockIdx.y * gridDim.x + blockIdx.x;
    int q = nwg >> 3, r = nwg & 7;
    int xcd = sid & 7, ix = sid >> 3;
    int logical = (xcd < r) ? xcd * (q + 1) + ix
                            : r * (q + 1) + (xcd - r) * q + ix;
    const int m0 = (logical / gridDim.x) * 256;
    const int n0 = (logical % gridDim.x) * BN;

    // staging: segment = 8 rows x 64 cols (1 KiB). lane l covers row (l>>3),
    // pre-swizzled global 16B-chunk (l&7)^(l>>3)  ->  LDS linear base+16B*l.
    const int lrow = lane >> 3;                    // 0..7
    const int lcol = ((lane & 7) ^ lrow) * 8;      // u16 units

    // hoisted per-thread global pointers; advance +64 u16 per stage call
    const u16* pA[AL];
    const u16* pB[BL];
    #pragma unroll
    for (int j = 0; j < AL; ++j)
        pA[j] = A + (size_t)(m0 + (wave * AL + j) * 8 + lrow) * KD + lcol;
    #pragma unroll
    for (int j = 0; j < BL; ++j)
        pB[j] = Bt + (size_t)(n0 + (wave * BL + j) * 8 + lrow) * KD + lcol;

    auto stage = [&](int slot) {
        #pragma unroll
        for (int j = 0; j < AL; ++j) {
            gload_lds16(pA[j], &Asm[slot * 256 * 64 + (wave * AL + j) * 512]);
            pA[j] += 64;
        }
        #pragma unroll
        for (int j = 0; j < BL; ++j) {
            gload_lds16(pB[j], &Bsm[slot * BN * 64 + (wave * BL + j) * 512]);
            pB[j] += 64;
        }
    };
    // swizzled fragment reads (row&7 == l15&7 since bases are multiples of 8)
    auto rdA = [&](int slot, int mi, int ks) -> bf16x8 {
        int row = wr * 128 + mi * 16 + l15;
        int ch  = (ks * 4 + kq) ^ (row & 7);
        return *reinterpret_cast<const bf16x8*>(&Asm[slot * 256 * 64 + row * 64 + ch * 8]);
    };
    auto rdB = [&](int slot, int ni, int ks) -> bf16x8 {
        int row = wc * 64 + ni * 16 + l15;
        int ch  = (ks * 4 + kq) ^ (row & 7);
        return *reinterpret_cast<const bf16x8*>(&Bsm[slot * BN * 64 + row * 64 + ch * 8]);
    };

    f32x4 acc[8][4] = {};
    bf16x8 alo[4][2], ahi[4][2], blo[2][2], bhi[2][2];

    // prologue: stage tile 0, publish, read q0 fragments
    stage(0);
    vmwait<0>();
    wg_barrier();
    #pragma unroll
    for (int mi = 0; mi < 4; ++mi) { alo[mi][0] = rdA(0, mi, 0); alo[mi][1] = rdA(0, mi, 1); }
    #pragma unroll
    for (int ni = 0; ni < 2; ++ni) { blo[ni][0] = rdB(0, ni, 0); blo[ni][1] = rdB(0, ni, 1); }

    #pragma unroll 2
    for (int t = 0; t < NT; ++t) {
        const int cur = t & 1;
        // ---- p0: stage next tile; read b_hi; MFMA q0 = alo x blo ----
        if (t + 1 < NT) stage(cur ^ 1);
        #pragma unroll
        for (int ni = 0; ni < 2; ++ni) { bhi[ni][0] = rdB(cur, ni + 2, 0); bhi[ni][1] = rdB(cur, ni + 2, 1); }
        __builtin_amdgcn_s_setprio(1);
        #pragma unroll
        for (int mi = 0; mi < 4; ++mi)
            #pragma unroll
            for (int ni = 0; ni < 2; ++ni) {
                acc[mi][ni] = __builtin_amdgcn_mfma_f32_16x16x32_bf16(alo[mi][0], blo[ni][0], acc[mi][ni], 0, 0, 0);
                acc[mi][ni] = __builtin_amdgcn_mfma_f32_16x16x32_bf16(alo[mi][1], blo[ni][1], acc[mi][ni], 0, 0, 0);
            }
        __builtin_amdgcn_s_setprio(0);
        // ---- p1: read a_hi; MFMA q1 = alo x bhi ----
        #pragma unroll
        for (int mi = 0; mi < 4; ++mi) { ahi[mi][0] = rdA(cur, mi + 4, 0); ahi[mi][1] = rdA(cur, mi + 4, 1); }
        __builtin_amdgcn_s_setprio(1);
        #pragma unroll
        for (int mi = 0; mi < 4; ++mi)
            #pragma unroll
            for (int ni = 0; ni < 2; ++ni) {
                acc[mi][ni + 2] = __builtin_amdgcn_mfma_f32_16x16x32_bf16(alo[mi][0], bhi[ni][0], acc[mi][ni + 2], 0, 0, 0);
                acc[mi][ni + 2] = __builtin_amdgcn_mfma_f32_16x16x32_bf16(alo[mi][1], bhi[ni][1], acc[mi][ni + 2], 0, 0, 0);
            }
        __builtin_amdgcn_s_setprio(0);
        // ---- p2: EARLY publish (stage issued 2 clusters ago); read next q0
        //          frags (covered by q2+q3); MFMA q2 = ahi x blo ----
        if (t + 1 < NT) {
            vmwait<0>();
            wg_barrier();
            #pragma unroll
            for (int mi = 0; mi < 4; ++mi) { alo[mi][0] = rdA(cur ^ 1, mi, 0); alo[mi][1] = rdA(cur ^ 1, mi, 1); }
        }
        __builtin_amdgcn_s_setprio(1);
        #pragma unroll
        for (int mi = 0; mi < 4; ++mi)
            #pragma unroll
            for (int ni = 0; ni < 2; ++ni) {
                acc[mi + 4][ni] = __builtin_amdgcn_mfma_f32_16x16x32_bf16(ahi[mi][0], blo[ni][0], acc[mi + 4][ni], 0, 0, 0);
                acc[mi + 4][ni] = __builtin_amdgcn_mfma_f32_16x16x32_bf16(ahi[mi][1], blo[ni][1], acc[mi + 4][ni], 0, 0, 0);
            }
        __builtin_amdgcn_s_setprio(0);
        // ---- p3: read next blo; MFMA q3 = ahi x bhi (barrier-free edge) ----
        if (t + 1 < NT) {
            #pragma unroll
            for (int ni = 0; ni < 2; ++ni) { blo[ni][0] = rdB(cur ^ 1, ni, 0); blo[ni][1] = rdB(cur ^ 1, ni, 1); }
        }
        __builtin_amdgcn_s_setprio(1);
        #pragma unroll
        for (int mi = 0; mi < 4; ++mi)
            #pragma unroll
            for (int ni = 0; ni < 2; ++ni) {
                acc[mi + 4][ni + 2] = __builtin_amdgcn_mfma_f32_16x16x32_bf16(ahi[mi][0], bhi[ni][0], acc[mi + 4][ni + 2], 0, 0, 0);
                acc[mi + 4][ni + 2] = __builtin_amdgcn_mfma_f32_16x16x32_bf16(ahi[mi][1], bhi[ni][1], acc[mi + 4][ni + 2], 0, 0, 0);
            }
        __builtin_amdgcn_s_setprio(0);
    }

    // ---- epilogue: acc -> LDS tile [256][LDSC] -> coalesced global stores --
    __syncthreads();                               // all LDS readers done
    #pragma unroll
    for (int ni = 0; ni < 4; ++ni) {
        int col = wc * 64 + ni * 16 + l15;
        float bv = bias[n0 + col];
        #pragma unroll
        for (int mi = 0; mi < 8; ++mi)
            #pragma unroll
            for (int r2 = 0; r2 < 4; ++r2) {
                int row = wr * 128 + mi * 16 + kq * 4 + r2;
                float v = acc[mi][ni][r2] + bv;
                if (RELU) v = v > 0.f ? v : 0.f;
                smem[row * LDSC + col] = f2bf(v);
            }
    }
    __syncthreads();
    constexpr int CHUNKS = BN / 8;                 // 16B chunks per row
    constexpr int ITERS  = 256 * CHUNKS / 512;
    #pragma unroll
    for (int it = 0; it < ITERS; ++it) {
        int task = it * 512 + tid;
        int row  = task / CHUNKS;
        int ch   = task % CHUNKS;
        uint4 v = *reinterpret_cast<const uint4*>(&smem[row * LDSC + ch * 8]);
        *reinterpret_cast<uint4*>(&C[(size_t)(m0 + row) * Ncols + n0 + ch * 8]) = v;
    }
}

// ---------------- layer 4: Y[M][32] f32 = A[M][512] @ Bt^T + bias (/ dscale) -
__global__ __launch_bounds__(256) void layer4_k(
    const u16* __restrict__ A, const u16* __restrict__ Bt,
    const float* __restrict__ bias, const float* __restrict__ dscale,
    float* __restrict__ Y, int M)
{
    __shared__ __attribute__((aligned(16))) u16 Bs[32 * 520];
    int tid = threadIdx.x;
    #pragma unroll
    for (int j = 0; j < 8; ++j) {
        int cch = tid + j * 256;          // 0..2047
        int row = cch >> 6;               // 0..31
        int ko  = (cch & 63) * 8;         // 0..504
        *reinterpret_cast<uint4*>(&Bs[row * 520 + ko]) =
            *reinterpret_cast<const uint4*>(Bt + (size_t)row * 512 + ko);
    }
    __syncthreads();
    int lane = tid & 63, wave = tid >> 6;
    int l15 = lane & 15, kq = lane >> 4;
    int rowb = blockIdx.x * 64 + wave * 16;
    f32x4 acc[2] = {};
    const u16* Arow = A + (size_t)(rowb + l15) * 512;
    #pragma unroll
    for (int ks = 0; ks < 16; ++ks) {
        bf16x8 a = *reinterpret_cast<const bf16x8*>(Arow + ks * 32 + kq * 8);
        #pragma unroll
        for (int ni = 0; ni < 2; ++ni) {
            bf16x8 b = *reinterpret_cast<const bf16x8*>(&Bs[(ni * 16 + l15) * 520 + ks * 32 + kq * 8]);
            acc[ni] = __builtin_amdgcn_mfma_f32_16x16x32_bf16(a, b, acc[ni], 0, 0, 0);
        }
    }
    #pragma unroll
    for (int ni = 0; ni < 2; ++ni) {
        int col = ni * 16 + l15;
        float bv = bias[col];
        #pragma unroll
        for (int r = 0; r < 4; ++r) {
            int rr = rowb + kq * 4 + r;
            float v = acc[ni][r] + bv;
            if (dscale) v /= dscale[rr];
            Y[(size_t)rr * 32 + col] = v;
        }
    }
}

// ---------------- gram: G[32][32] += sum_i y_i y_i^T ----------------
__global__ __launch_bounds__(256) void gram_k(const float* __restrict__ Y,
                                              float* __restrict__ G) {
    __shared__ float ys[8][32];
    const int ROWS = NPTS / 256;            // grid must be 256 blocks
    int base = blockIdx.x * ROWS;
    int tid = threadIdx.x;
    int r = tid >> 3, c0 = (tid & 7) * 4;
    float a0 = 0, a1 = 0, a2 = 0, a3 = 0;
    for (int i0 = 0; i0 < ROWS; i0 += 8) {
        ys[tid >> 5][tid & 31] = Y[(size_t)(base + i0 + (tid >> 5)) * 32 + (tid & 31)];
        __syncthreads();
        #pragma unroll
        for (int q = 0; q < 8; ++q) {
            float yr = ys[q][r];
            a0 += yr * ys[q][c0];     a1 += yr * ys[q][c0 + 1];
            a2 += yr * ys[q][c0 + 2]; a3 += yr * ys[q][c0 + 3];
        }
        __syncthreads();
    }
    atomicAdd(&G[r * 32 + c0], a0);     atomicAdd(&G[r * 32 + c0 + 1], a1);
    atomicAdd(&G[r * 32 + c0 + 2], a2); atomicAdd(&G[r * 32 + c0 + 3], a3);
}

// -------- cholesky + triangular inverse (fp64, 256 threads, parallel) -------
__global__ __launch_bounds__(256) void chol_oper_k(const float* __restrict__ G,
                                                   float* __restrict__ oper) {
    __shared__ double A[32][33];
    __shared__ double xcol[32][33];          // xcol[row][col]
    const int t  = threadIdx.x;
    const int j  = t & 31;
    const int i0 = t >> 5;                   // 0..7

    #pragma unroll
    for (int q = 0; q < 4; ++q) {
        int i = i0 + q * 8;
        A[i][j] = (double)G[i * 32 + j] + (i == j ? 1e-7 : 0.0);
    }
    __syncthreads();

    for (int k = 0; k < 32; ++k) {
        double akk = A[k][k];
        __syncthreads();
        if (j == k) {
            double s = sqrt(akk);
            #pragma unroll
            for (int q = 0; q < 4; ++q) {
                int i = i0 + q * 8;
                if (i == k)      A[i][k] = s;
                else if (i > k)  A[i][k] /= s;
            }
        }
        __syncthreads();
        if (j > k) {
            double ajk = A[j][k];
            #pragma unroll
            for (int q = 0; q < 4; ++q) {
                int i = i0 + q * 8;
                if (i >= j) A[i][j] -= A[i][k] * ajk;
            }
        }
        __syncthreads();
    }

    const int c = j;
    double s[4] = {0.0, 0.0, 0.0, 0.0};
    for (int jj = 0; jj < 32; ++jj) {
        if (i0 == (jj & 7) && jj >= c) {
            double rhs = (jj == c) ? 1.0 : 0.0;
            xcol[jj][c] = (rhs - s[jj >> 3]) / A[jj][jj];
        }
        __syncthreads();
        if (jj >= c) {
            double x = xcol[jj][c];
            #pragma unroll
            for (int q = 0; q < 4; ++q) {
                int r = i0 + q * 8;
                if (r > jj) s[q] += A[r][jj] * x;
            }
        }
        __syncthreads();
    }
    #pragma unroll
    for (int q = 0; q < 4; ++q) {
        int r = i0 + q * 8;
        oper[c * 32 + r] = (r >= c) ? (float)(xcol[r][c] * 256.0) : 0.f;
    }
}

// ---- loss partials: part[b] = sum_block ||y_i - y_j||^2 * (d2[i]+d2[j]) ----
__global__ __launch_bounds__(256) void loss_k(
    const float* __restrict__ Y, const int* __restrict__ nn,
    const float* __restrict__ d2, double* __restrict__ part) {
    int e = blockIdx.x * 256 + threadIdx.x;    // over NPTS*KNN
    int i = e >> 4;
    int j = nn[e];
    const float4* yi = reinterpret_cast<const float4*>(Y + (size_t)i * 32);
    const float4* yj = reinterpret_cast<const float4*>(Y + (size_t)j * 32);
    float s = 0.f;
    #pragma unroll
    for (int q = 0; q < 8; ++q) {
        float4 a = yi[q], b = yj[q];
        float dx = a.x - b.x, dy = a.y - b.y, dz = a.z - b.z, dw = a.w - b.w;
        s += dx * dx + dy * dy + dz * dz + dw * dw;
    }
    double local = (double)s * ((double)d2[i] + (double)d2[j]);
    #pragma unroll
    for (int off = 32; off > 0; off >>= 1) local += __shfl_down(local, off);
    __shared__ double wsum[4];
    if ((threadIdx.x & 63) == 0) wsum[threadIdx.x >> 6] = local;
    __syncthreads();
    if (threadIdx.x == 0)
        part[blockIdx.x] = wsum[0] + wsum[1] + wsum[2] + wsum[3];
}

__global__ __launch_bounds__(256) void reduce_part_k(
    const double* __restrict__ part, int n, float* __restrict__ out) {
    double s = 0.0;
    for (int i = threadIdx.x; i < n; i += 256) s += part[i];
    #pragma unroll
    for (int off = 32; off > 0; off >>= 1) s += __shfl_down(s, off);
    __shared__ double wsum[4];
    if ((threadIdx.x & 63) == 0) wsum[threadIdx.x >> 6] = s;
    __syncthreads();
    if (threadIdx.x == 0)
        out[0] = (float)((wsum[0] + wsum[1] + wsum[2] + wsum[3]) / (double)NPTS);
}

// ---------------------------------------------------------------------------
extern "C" void kernel_launch(void* const* d_in, const int* in_sizes, int n_in,
                              void* d_out, int out_size, void* d_ws, size_t ws_size,
                              hipStream_t stream) {
    const float* x1     = (const float*)d_in[0];
    const float* x2     = (const float*)d_in[1];
    const float* dists1 = (const float*)d_in[2];
    const int*   nn1    = (const int*)  d_in[3];
    const float* dists2 = (const float*)d_in[4];
    const int*   nn2    = (const int*)  d_in[5];
    const float* W1 = (const float*)d_in[6];  const float* b1 = (const float*)d_in[7];
    const float* W2 = (const float*)d_in[8];  const float* b2 = (const float*)d_in[9];
    const float* W3 = (const float*)d_in[10]; const float* b3 = (const float*)d_in[11];
    const float* W4 = (const float*)d_in[12]; const float* b4 = (const float*)d_in[13];

    char* ws = (char*)d_ws;
    size_t off = 0;
    auto alloc = [&](size_t bytes) { char* p = ws + off; off += (bytes + 255) & ~(size_t)255; return p; };
    u16*    xb   = (u16*)   alloc((size_t)NPTS * INDIM * 2);
    float*  yraw = (float*) alloc((size_t)NPTS * ODIM * 4);
    float*  yop  = (float*) alloc((size_t)NPTS * ODIM * 4);
    u16*    W1t  = (u16*)   alloc((size_t)HID * INDIM * 2);
    u16*    W2t  = (u16*)   alloc((size_t)HID * HID * 2);
    u16*    W3t  = (u16*)   alloc((size_t)HID2 * HID * 2);
    u16*    W4t  = (u16*)   alloc((size_t)ODIM * HID2 * 2);
    u16*    W4tP = (u16*)   alloc((size_t)ODIM * HID2 * 2);
    float*  b4f  = (float*) alloc(ODIM * 4);
    float*  d1   = (float*) alloc((size_t)NPTS * 4);
    float*  d2   = (float*) alloc((size_t)NPTS * 4);
    float*  wb1  = (float*) alloc((size_t)NPTS * KNN * 4);
    float*  wb2  = (float*) alloc((size_t)NPTS * KNN * 4);
    float*  dpart= (float*) alloc((size_t)2 * ESL * NPTS * 4);
    float*  gram = (float*) alloc(32 * 32 * 4);
    float*  oper = (float*) alloc(32 * 32 * 4);
    double* part = (double*)alloc((size_t)(NPTS * KNN / 256) * 8);
    size_t fixed = off;
    (void)in_sizes; (void)n_in; (void)out_size;

    // Chunk the MLP. Cap at 32768 rows: cb1+cb2 (134MB) + fixed buffers stay
    // L3-resident; cb buffers are REUSED across chunks.
    int chunk = 2048;
    for (int c = 32768; c >= 2048; c >>= 1)
        if (fixed + (size_t)c * 1024 * 2 * 2 + 512 <= ws_size) { chunk = c; break; }
    u16* cb1 = (u16*)alloc((size_t)chunk * HID * 2);
    u16* cb2 = (u16*)alloc((size_t)chunk * HID * 2);

    // weight transposes + zero-init
    trans_bf16_k<<<(INDIM * HID + 255) / 256, 256, 0, stream>>>(W1, W1t, INDIM, HID);
    trans_bf16_k<<<(HID * HID + 255) / 256, 256, 0, stream>>>(W2, W2t, HID, HID);
    trans_bf16_k<<<(HID * HID2 + 255) / 256, 256, 0, stream>>>(W3, W3t, HID, HID2);
    trans_bf16_k<<<(HID2 * ODIM + 255) / 256, 256, 0, stream>>>(W4, W4t, HID2, ODIM);
    hipMemsetAsync(gram, 0, 32 * 32 * 4, stream);

    // degree: 3-stage atomic-free
    edgew_k<<<dim3(NPTS / 256, 2), 256, 0, stream>>>(dists1, wb1, d1, dists2, wb2, d2);
    scatter_k<<<dim3(ESL, 4, 2), 512, 0, stream>>>(nn1, wb1, nn2, wb2, dpart);
    dreduce_k<<<dim3(NPTS / 256, 2), 256, 0, stream>>>(dpart, d1, d2);

    dim3 g12(HID / 256, chunk / 256);    // 4 x (chunk/256)
    dim3 g3(HID2 / 256, chunk / 256);    // 2 x (chunk/256)

    for (int pass = 0; pass < 2; ++pass) {
        const float* x = pass == 0 ? x1 : x2;
        cvt_bf16_k<<<(NPTS * INDIM / 4 + 255) / 256, 256, 0, stream>>>(x, xb, NPTS * INDIM / 4);
        for (int s0 = 0; s0 < NPTS; s0 += chunk) {
            const u16* Ain = xb + (size_t)s0 * INDIM;
            gemm256_k<true, INDIM><<<g12, 512, 0, stream>>>(Ain, W1t, b1, cb1, chunk, HID);
            gemm256_k<true, HID><<<g12, 512, 0, stream>>>(cb1, W2t, b2, cb2, chunk, HID);
            gemm256_k<true, HID><<<g3, 512, 0, stream>>>(cb2, W3t, b3, cb1, chunk, HID2);
            if (pass == 0)
                layer4_k<<<chunk / 64, 256, 0, stream>>>(
                    cb1, W4t, b4, d1 + s0, yraw + (size_t)s0 * ODIM, chunk);
            else
                layer4_k<<<chunk / 64, 256, 0, stream>>>(
                    cb1, W4tP, b4f, d2 + s0, yop + (size_t)s0 * ODIM, chunk);
        }
        if (pass == 0) {
            gram_k<<<256, 256, 0, stream>>>(yraw, gram);
            chol_oper_k<<<1, 256, 0, stream>>>(gram, oper);
            oper_fold_k<<<(HID2 * ODIM + ODIM + 255) / 256, 256, 0, stream>>>(
                W4, b4, oper, W4tP, b4f);
        } else {
            loss_k<<<NPTS * KNN / 256, 256, 0, stream>>>(yop, nn2, d2, part);
            reduce_part_k<<<1, 256, 0, stream>>>(part, NPTS * KNN / 256, (float*)d_out);
        }
    }
}

// Round 19
// 712.076 us; speedup vs baseline: 1.2906x; 1.2906x over previous
//
#include <hip/hip_runtime.h>

// ---------------------------------------------------------------------------
// SpectralNet loss pipeline on MI355X.  (r19 = r17 verbatim — best measured:
// 713us total; r18's pointer-hoist/unroll-2 experiment spilled to scratch,
// WRITE 70->145MB, GEMM 79->122us, and is fully reverted.)
//   pass1: y1 = MLP(x1)/d1 -> gram -> cholesky -> operator = inv(L)^T*sqrt(N)
//   pass2: y  = (MLP(x2) @ operator)/d2 -> loss = sum_e de*(d2[i]+d2[j])/N
// GEMM: 256x256 tile, BK=64, 512 thr, dbuf LDS, software-pipelined fragments
// with EARLY publish (vmwait+barrier at p2), setprio clusters, XOR-swizzled
// LDS via pre-swizzled global source, bijective XCD swizzle, coalesced C
// epilogue through LDS. Operator folded into pass-2 layer4 (W4'=W4@O).
// Degree: atomic-free 3-stage. Cholesky: parallel fp64.
// ---------------------------------------------------------------------------

#define NPTS  65536
#define KNN   16
#define INDIM 128
#define HID   1024
#define HID2  512
#define ODIM  32
#define ESL   32          // edge slices for degree scatter

typedef unsigned short u16;
typedef unsigned int   u32;
typedef __attribute__((ext_vector_type(8))) short bf16x8;
typedef __attribute__((ext_vector_type(4))) float f32x4;

__device__ __forceinline__ u16 f2bf(float v) {
    union { float f; unsigned u; } x; x.f = v;
    unsigned r = x.u + 0x7fffu + ((x.u >> 16) & 1u);   // round-to-nearest-even
    return (u16)(r >> 16);
}

__device__ __forceinline__ void gload_lds16(const u16* g, u16* l) {
    __builtin_amdgcn_global_load_lds(
        (const __attribute__((address_space(1))) u32*)g,
        (__attribute__((address_space(3))) u32*)l, 16, 0, 0);
}

template <int N> __device__ __forceinline__ void vmwait() {
    asm volatile("s_waitcnt vmcnt(%0)" :: "n"(N) : "memory");
}
__device__ __forceinline__ void wg_barrier() {
    asm volatile("s_barrier" ::: "memory");
}

// ---------------- conversion / transpose ----------------
__global__ void cvt_bf16_k(const float* __restrict__ in, u16* __restrict__ out, int n4) {
    int i = blockIdx.x * blockDim.x + threadIdx.x;
    if (i >= n4) return;
    float4 v = reinterpret_cast<const float4*>(in)[i];
    unsigned lo = (unsigned)f2bf(v.x) | ((unsigned)f2bf(v.y) << 16);
    unsigned hi = (unsigned)f2bf(v.z) | ((unsigned)f2bf(v.w) << 16);
    reinterpret_cast<uint2*>(out)[i] = make_uint2(lo, hi);
}

// W [rows][cols] f32 -> Wt [cols][rows] bf16   (write-coalesced)
__global__ void trans_bf16_k(const float* __restrict__ W, u16* __restrict__ Wt,
                             int rows, int cols) {
    int idx = blockIdx.x * blockDim.x + threadIdx.x;
    if (idx >= rows * cols) return;
    int o = idx / rows, i = idx - o * rows;
    Wt[idx] = f2bf(W[(size_t)i * cols + o]);
}

// ---- fold operator into layer 4:  W4t'[o][h] = sum_j W4[h][j] O[j][o],
//      b4f[o] = sum_j b4[j] O[j][o].  (O = oper, row-major [32][32])
__global__ void oper_fold_k(const float* __restrict__ W4, const float* __restrict__ b4,
                            const float* __restrict__ oper,
                            u16* __restrict__ W4tP, float* __restrict__ b4f) {
    __shared__ float op[1024];
    int tid = threadIdx.x;
    #pragma unroll
    for (int j = tid; j < 1024; j += 256) op[j] = oper[j];
    __syncthreads();
    int idx = blockIdx.x * 256 + tid;              // 0 .. 512*32+32-1
    if (idx < HID2 * ODIM) {
        int o = idx & 31, h = idx >> 5;
        float s = 0.f;
        #pragma unroll
        for (int j = 0; j < 32; ++j) s += W4[h * 32 + j] * op[j * 32 + o];
        W4tP[o * HID2 + h] = f2bf(s);
    } else if (idx < HID2 * ODIM + ODIM) {
        int o = idx - HID2 * ODIM;
        float s = 0.f;
        #pragma unroll
        for (int j = 0; j < 32; ++j) s += b4[j] * op[j * 32 + o];
        b4f[o] = s;
    }
}

// ---------------- degree stage 1: edge weights + row half ----------------
__global__ void edgew_k(const float* __restrict__ dists1, float* __restrict__ w1,
                        float* __restrict__ dr1,
                        const float* __restrict__ dists2, float* __restrict__ w2,
                        float* __restrict__ dr2) {
    const float* dists = blockIdx.y ? dists2 : dists1;
    float*       wbuf  = blockIdx.y ? w2     : w1;
    float*       drow  = blockIdx.y ? dr2    : dr1;
    int i = blockIdx.x * blockDim.x + threadIdx.x;
    if (i >= NPTS) return;
    const float4* dr = reinterpret_cast<const float4*>(dists + (size_t)i * KNN);
    float4 a = dr[0], b = dr[1], c = dr[2], e = dr[3];
    float buf[KNN] = {a.x,a.y,a.z,a.w,b.x,b.y,b.z,b.w,c.x,c.y,c.z,c.w,e.x,e.y,e.z,e.w};
    float s = 0.f;
    #pragma unroll
    for (int k = 0; k < KNN; ++k) s += buf[k];
    float sigma = s * (1.f / KNN);
    float inv2s2 = 1.f / (2.f * sigma * sigma);
    float w[KNN];
    float rs = 0.f;
    #pragma unroll
    for (int k = 0; k < KNN; ++k) { w[k] = __expf(-buf[k] * buf[k] * inv2s2); rs += w[k]; }
    drow[i] = 0.5f * rs;
    float4* wo = reinterpret_cast<float4*>(wbuf + (size_t)i * KNN);
    wo[0] = make_float4(w[0], w[1], w[2], w[3]);
    wo[1] = make_float4(w[4], w[5], w[6], w[7]);
    wo[2] = make_float4(w[8], w[9], w[10], w[11]);
    wo[3] = make_float4(w[12], w[13], w[14], w[15]);
}

// ---------------- degree stage 2: LDS-binned scatter into partials ----------
__global__ __launch_bounds__(512) void scatter_k(
    const int* __restrict__ nn1, const float* __restrict__ w1,
    const int* __restrict__ nn2, const float* __restrict__ w2,
    float* __restrict__ partial) {
    __shared__ float bins[16384];
    const int slice = blockIdx.x, range = blockIdx.y, g = blockIdx.z;
    const int* nn   = g ? nn2 : nn1;
    const float* wb = g ? w2  : w1;
    for (int b = threadIdx.x; b < 16384; b += 512) bins[b] = 0.f;
    __syncthreads();
    const int per4  = (NPTS * KNN / ESL) >> 2;       // 8192 int4 per slice
    const int base4 = slice * per4;
    const int4*   nn4 = reinterpret_cast<const int4*>(nn);
    const float4* w4  = reinterpret_cast<const float4*>(wb);
    #pragma unroll 2
    for (int k = 0; k < per4 / 512; ++k) {           // 16 iterations
        int e4 = base4 + k * 512 + threadIdx.x;
        int4   idx = nn4[e4];
        float4 wv  = w4[e4];
        if ((idx.x >> 14) == range) atomicAdd(&bins[idx.x & 16383], wv.x);
        if ((idx.y >> 14) == range) atomicAdd(&bins[idx.y & 16383], wv.y);
        if ((idx.z >> 14) == range) atomicAdd(&bins[idx.z & 16383], wv.z);
        if ((idx.w >> 14) == range) atomicAdd(&bins[idx.w & 16383], wv.w);
    }
    __syncthreads();
    float* dst = partial + ((size_t)(g * ESL + slice) << 16) + (range << 14);
    for (int b = threadIdx.x; b < 16384; b += 512) dst[b] = bins[b];
}

// ---------------- degree stage 3: d[i] = rowhalf + 0.5*sum_slices -----------
__global__ __launch_bounds__(256) void dreduce_k(
    const float* __restrict__ partial, float* __restrict__ d1, float* __restrict__ d2) {
    int i = blockIdx.x * 256 + threadIdx.x;      // 0..65535
    int g = blockIdx.y;
    const float* p = partial + ((size_t)(g * ESL) << 16) + i;
    float s = 0.f;
    #pragma unroll 8
    for (int sl = 0; sl < ESL; ++sl) s += p[(size_t)sl << 16];
    float* d = g ? d2 : d1;
    d[i] += 0.5f * s;
}

// ---------------- GEMM: C = relu(A @ Bt^T + bias), bf16 in/out --------------
// BM=256, BN=256, BK=64, 512 threads = 8 waves (2 M x 4 N), per-wave 128x64.
// Early-publish software pipeline (r14/r17, best measured).
template <bool RELU>
__global__ __launch_bounds__(512) void gemm256_k(
    const u16* __restrict__ A, const u16* __restrict__ Bt,
    const float* __restrict__ bias, u16* __restrict__ C,
    int M, int Ncols, int Kd)
{
    constexpr int BN   = 256;
    constexpr int AL   = 4;                // A gload_lds per thread per K-tile
    constexpr int BL   = 4;                // B gload_lds per thread per K-tile
    constexpr int A_U16  = 2 * 256 * 64;            // dbuf A
    constexpr int B_U16  = 2 * BN * 64;             // dbuf B
    constexpr int LDSC   = BN + 16;                 // epilogue row stride (u16)
    constexpr int EP_U16 = 256 * LDSC;
    constexpr int SM_U16 = (A_U16 + B_U16 > EP_U16) ? (A_U16 + B_U16) : EP_U16;

    __shared__ __attribute__((aligned(16))) u16 smem[SM_U16];
    u16* Asm = smem;                 // [2][256*64]
    u16* Bsm = smem + A_U16;         // [2][BN*64]

    const int tid  = threadIdx.x;
    const int lane = tid & 63;
    const int wave = tid >> 6;       // 0..7
    const int wr   = wave >> 2;      // 0..1
    const int wc   = wave & 3;       // 0..3
    const int l15  = lane & 15;
    const int kq   = lane >> 4;      // 0..3

    // bijective XCD-chunked swizzle of the linear block id (T1/m204)
    const int nwg = gridDim.x * gridDim.y;
    int sid = blockIdx.y * gridDim.x + blockIdx.x;
    int q = nwg >> 3, r = nwg & 7;
    int xcd = sid & 7, ix = sid >> 3;
    int logical = (xcd < r) ? xcd * (q + 1) + ix
                            : r * (q + 1) + (xcd - r) * q + ix;
    const int m0 = (logical / gridDim.x) * 256;
    const int n0 = (logical % gridDim.x) * BN;

    // staging: segment = 8 rows x 64 cols (1 KiB). lane l covers row (l>>3),
    // pre-swizzled global 16B-chunk (l&7)^(l>>3)  ->  LDS linear base+16B*l.
    const int lrow = lane >> 3;                    // 0..7
    const int lcol = ((lane & 7) ^ lrow) * 8;      // u16 units

    auto stage = [&](int slot, int kt) {
        #pragma unroll
        for (int j = 0; j < AL; ++j) {
            int seg = wave * AL + j;               // 0..31
            gload_lds16(A + (size_t)(m0 + seg * 8 + lrow) * Kd + kt + lcol,
                        &Asm[slot * 256 * 64 + seg * 512]);
        }
        #pragma unroll
        for (int j = 0; j < BL; ++j) {
            int seg = wave * BL + j;
            gload_lds16(Bt + (size_t)(n0 + seg * 8 + lrow) * Kd + kt + lcol,
                        &Bsm[slot * BN * 64 + seg * 512]);
        }
    };
    // swizzled fragment reads (row&7 == l15&7 since bases are multiples of 8)
    auto rdA = [&](int slot, int mi, int ks) -> bf16x8 {
        int row = wr * 128 + mi * 16 + l15;
        int ch  = (ks * 4 + kq) ^ (row & 7);
        return *reinterpret_cast<const bf16x8*>(&Asm[slot * 256 * 64 + row * 64 + ch * 8]);
    };
    auto rdB = [&](int slot, int ni, int ks) -> bf16x8 {
        int row = wc * 64 + ni * 16 + l15;
        int ch  = (ks * 4 + kq) ^ (row & 7);
        return *reinterpret_cast<const bf16x8*>(&Bsm[slot * BN * 64 + row * 64 + ch * 8]);
    };

    const int NT = Kd >> 6;
    f32x4 acc[8][4] = {};
    bf16x8 alo[4][2], ahi[4][2], blo[2][2], bhi[2][2];

    // prologue: stage tile 0, publish, read q0 fragments
    stage(0, 0);
    vmwait<0>();
    wg_barrier();
    #pragma unroll
    for (int mi = 0; mi < 4; ++mi) { alo[mi][0] = rdA(0, mi, 0); alo[mi][1] = rdA(0, mi, 1); }
    #pragma unroll
    for (int ni = 0; ni < 2; ++ni) { blo[ni][0] = rdB(0, ni, 0); blo[ni][1] = rdB(0, ni, 1); }

    for (int t = 0; t < NT; ++t) {
        const int cur = t & 1;
        // ---- p0: stage next tile; read b_hi; MFMA q0 = alo x blo ----
        if (t + 1 < NT) stage(cur ^ 1, (t + 1) << 6);
        #pragma unroll
        for (int ni = 0; ni < 2; ++ni) { bhi[ni][0] = rdB(cur, ni + 2, 0); bhi[ni][1] = rdB(cur, ni + 2, 1); }
        __builtin_amdgcn_s_setprio(1);
        #pragma unroll
        for (int mi = 0; mi < 4; ++mi)
            #pragma unroll
            for (int ni = 0; ni < 2; ++ni) {
                acc[mi][ni] = __builtin_amdgcn_mfma_f32_16x16x32_bf16(alo[mi][0], blo[ni][0], acc[mi][ni], 0, 0, 0);
                acc[mi][ni] = __builtin_amdgcn_mfma_f32_16x16x32_bf16(alo[mi][1], blo[ni][1], acc[mi][ni], 0, 0, 0);
            }
        __builtin_amdgcn_s_setprio(0);
        // ---- p1: read a_hi; MFMA q1 = alo x bhi ----
        #pragma unroll
        for (int mi = 0; mi < 4; ++mi) { ahi[mi][0] = rdA(cur, mi + 4, 0); ahi[mi][1] = rdA(cur, mi + 4, 1); }
        __builtin_amdgcn_s_setprio(1);
        #pragma unroll
        for (int mi = 0; mi < 4; ++mi)
            #pragma unroll
            for (int ni = 0; ni < 2; ++ni) {
                acc[mi][ni + 2] = __builtin_amdgcn_mfma_f32_16x16x32_bf16(alo[mi][0], bhi[ni][0], acc[mi][ni + 2], 0, 0, 0);
                acc[mi][ni + 2] = __builtin_amdgcn_mfma_f32_16x16x32_bf16(alo[mi][1], bhi[ni][1], acc[mi][ni + 2], 0, 0, 0);
            }
        __builtin_amdgcn_s_setprio(0);
        // ---- p2: EARLY publish (stage issued 2 clusters ago); read next q0
        //          frags (covered by q2+q3); MFMA q2 = ahi x blo ----
        if (t + 1 < NT) {
            vmwait<0>();
            wg_barrier();
            #pragma unroll
            for (int mi = 0; mi < 4; ++mi) { alo[mi][0] = rdA(cur ^ 1, mi, 0); alo[mi][1] = rdA(cur ^ 1, mi, 1); }
        }
        __builtin_amdgcn_s_setprio(1);
        #pragma unroll
        for (int mi = 0; mi < 4; ++mi)
            #pragma unroll
            for (int ni = 0; ni < 2; ++ni) {
                acc[mi + 4][ni] = __builtin_amdgcn_mfma_f32_16x16x32_bf16(ahi[mi][0], blo[ni][0], acc[mi + 4][ni], 0, 0, 0);
                acc[mi + 4][ni] = __builtin_amdgcn_mfma_f32_16x16x32_bf16(ahi[mi][1], blo[ni][1], acc[mi + 4][ni], 0, 0, 0);
            }
        __builtin_amdgcn_s_setprio(0);
        // ---- p3: read next blo; MFMA q3 = ahi x bhi (barrier-free edge) ----
        if (t + 1 < NT) {
            #pragma unroll
            for (int ni = 0; ni < 2; ++ni) { blo[ni][0] = rdB(cur ^ 1, ni, 0); blo[ni][1] = rdB(cur ^ 1, ni, 1); }
        }
        __builtin_amdgcn_s_setprio(1);
        #pragma unroll
        for (int mi = 0; mi < 4; ++mi)
            #pragma unroll
            for (int ni = 0; ni < 2; ++ni) {
                acc[mi + 4][ni + 2] = __builtin_amdgcn_mfma_f32_16x16x32_bf16(ahi[mi][0], bhi[ni][0], acc[mi + 4][ni + 2], 0, 0, 0);
                acc[mi + 4][ni + 2] = __builtin_amdgcn_mfma_f32_16x16x32_bf16(ahi[mi][1], bhi[ni][1], acc[mi + 4][ni + 2], 0, 0, 0);
            }
        __builtin_amdgcn_s_setprio(0);
    }

    // ---- epilogue: acc -> LDS tile [256][LDSC] -> coalesced global stores --
    __syncthreads();                               // all LDS readers done
    #pragma unroll
    for (int ni = 0; ni < 4; ++ni) {
        int col = wc * 64 + ni * 16 + l15;
        float bv = bias[n0 + col];
        #pragma unroll
        for (int mi = 0; mi < 8; ++mi)
            #pragma unroll
            for (int r2 = 0; r2 < 4; ++r2) {
                int row = wr * 128 + mi * 16 + kq * 4 + r2;
                float v = acc[mi][ni][r2] + bv;
                if (RELU) v = v > 0.f ? v : 0.f;
                smem[row * LDSC + col] = f2bf(v);
            }
    }
    __syncthreads();
    constexpr int CHUNKS = BN / 8;                 // 16B chunks per row
    constexpr int ITERS  = 256 * CHUNKS / 512;
    #pragma unroll
    for (int it = 0; it < ITERS; ++it) {
        int task = it * 512 + tid;
        int row  = task / CHUNKS;
        int ch   = task % CHUNKS;
        uint4 v = *reinterpret_cast<const uint4*>(&smem[row * LDSC + ch * 8]);
        *reinterpret_cast<uint4*>(&C[(size_t)(m0 + row) * Ncols + n0 + ch * 8]) = v;
    }
}

// ---------------- layer 4: Y[M][32] f32 = A[M][512] @ Bt^T + bias (/ dscale) -
__global__ __launch_bounds__(256) void layer4_k(
    const u16* __restrict__ A, const u16* __restrict__ Bt,
    const float* __restrict__ bias, const float* __restrict__ dscale,
    float* __restrict__ Y, int M)
{
    __shared__ __attribute__((aligned(16))) u16 Bs[32 * 520];
    int tid = threadIdx.x;
    #pragma unroll
    for (int j = 0; j < 8; ++j) {
        int cch = tid + j * 256;          // 0..2047
        int row = cch >> 6;               // 0..31
        int ko  = (cch & 63) * 8;         // 0..504
        *reinterpret_cast<uint4*>(&Bs[row * 520 + ko]) =
            *reinterpret_cast<const uint4*>(Bt + (size_t)row * 512 + ko);
    }
    __syncthreads();
    int lane = tid & 63, wave = tid >> 6;
    int l15 = lane & 15, kq = lane >> 4;
    int rowb = blockIdx.x * 64 + wave * 16;
    f32x4 acc[2] = {};
    const u16* Arow = A + (size_t)(rowb + l15) * 512;
    #pragma unroll
    for (int ks = 0; ks < 16; ++ks) {
        bf16x8 a = *reinterpret_cast<const bf16x8*>(Arow + ks * 32 + kq * 8);
        #pragma unroll
        for (int ni = 0; ni < 2; ++ni) {
            bf16x8 b = *reinterpret_cast<const bf16x8*>(&Bs[(ni * 16 + l15) * 520 + ks * 32 + kq * 8]);
            acc[ni] = __builtin_amdgcn_mfma_f32_16x16x32_bf16(a, b, acc[ni], 0, 0, 0);
        }
    }
    #pragma unroll
    for (int ni = 0; ni < 2; ++ni) {
        int col = ni * 16 + l15;
        float bv = bias[col];
        #pragma unroll
        for (int r = 0; r < 4; ++r) {
            int rr = rowb + kq * 4 + r;
            float v = acc[ni][r] + bv;
            if (dscale) v /= dscale[rr];
            Y[(size_t)rr * 32 + col] = v;
        }
    }
}

// ---------------- gram: G[32][32] += sum_i y_i y_i^T ----------------
__global__ __launch_bounds__(256) void gram_k(const float* __restrict__ Y,
                                              float* __restrict__ G) {
    __shared__ float ys[8][32];
    const int ROWS = NPTS / 256;            // grid must be 256 blocks
    int base = blockIdx.x * ROWS;
    int tid = threadIdx.x;
    int r = tid >> 3, c0 = (tid & 7) * 4;
    float a0 = 0, a1 = 0, a2 = 0, a3 = 0;
    for (int i0 = 0; i0 < ROWS; i0 += 8) {
        ys[tid >> 5][tid & 31] = Y[(size_t)(base + i0 + (tid >> 5)) * 32 + (tid & 31)];
        __syncthreads();
        #pragma unroll
        for (int q = 0; q < 8; ++q) {
            float yr = ys[q][r];
            a0 += yr * ys[q][c0];     a1 += yr * ys[q][c0 + 1];
            a2 += yr * ys[q][c0 + 2]; a3 += yr * ys[q][c0 + 3];
        }
        __syncthreads();
    }
    atomicAdd(&G[r * 32 + c0], a0);     atomicAdd(&G[r * 32 + c0 + 1], a1);
    atomicAdd(&G[r * 32 + c0 + 2], a2); atomicAdd(&G[r * 32 + c0 + 3], a3);
}

// -------- cholesky + triangular inverse (fp64, 256 threads, parallel) -------
__global__ __launch_bounds__(256) void chol_oper_k(const float* __restrict__ G,
                                                   float* __restrict__ oper) {
    __shared__ double A[32][33];
    __shared__ double xcol[32][33];          // xcol[row][col]
    const int t  = threadIdx.x;
    const int j  = t & 31;
    const int i0 = t >> 5;                   // 0..7

    #pragma unroll
    for (int q = 0; q < 4; ++q) {
        int i = i0 + q * 8;
        A[i][j] = (double)G[i * 32 + j] + (i == j ? 1e-7 : 0.0);
    }
    __syncthreads();

    for (int k = 0; k < 32; ++k) {
        double akk = A[k][k];
        __syncthreads();
        if (j == k) {
            double s = sqrt(akk);
            #pragma unroll
            for (int q = 0; q < 4; ++q) {
                int i = i0 + q * 8;
                if (i == k)      A[i][k] = s;
                else if (i > k)  A[i][k] /= s;
            }
        }
        __syncthreads();
        if (j > k) {
            double ajk = A[j][k];
            #pragma unroll
            for (int q = 0; q < 4; ++q) {
                int i = i0 + q * 8;
                if (i >= j) A[i][j] -= A[i][k] * ajk;
            }
        }
        __syncthreads();
    }

    const int c = j;
    double s[4] = {0.0, 0.0, 0.0, 0.0};
    for (int jj = 0; jj < 32; ++jj) {
        if (i0 == (jj & 7) && jj >= c) {
            double rhs = (jj == c) ? 1.0 : 0.0;
            xcol[jj][c] = (rhs - s[jj >> 3]) / A[jj][jj];
        }
        __syncthreads();
        if (jj >= c) {
            double x = xcol[jj][c];
            #pragma unroll
            for (int q = 0; q < 4; ++q) {
                int r = i0 + q * 8;
                if (r > jj) s[q] += A[r][jj] * x;
            }
        }
        __syncthreads();
    }
    #pragma unroll
    for (int q = 0; q < 4; ++q) {
        int r = i0 + q * 8;
        oper[c * 32 + r] = (r >= c) ? (float)(xcol[r][c] * 256.0) : 0.f;
    }
}

// ---- loss partials: part[b] = sum_block ||y_i - y_j||^2 * (d2[i]+d2[j]) ----
__global__ __launch_bounds__(256) void loss_k(
    const float* __restrict__ Y, const int* __restrict__ nn,
    const float* __restrict__ d2, double* __restrict__ part) {
    int e = blockIdx.x * 256 + threadIdx.x;    // over NPTS*KNN
    int i = e >> 4;
    int j = nn[e];
    const float4* yi = reinterpret_cast<const float4*>(Y + (size_t)i * 32);
    const float4* yj = reinterpret_cast<const float4*>(Y + (size_t)j * 32);
    float s = 0.f;
    #pragma unroll
    for (int q = 0; q < 8; ++q) {
        float4 a = yi[q], b = yj[q];
        float dx = a.x - b.x, dy = a.y - b.y, dz = a.z - b.z, dw = a.w - b.w;
        s += dx * dx + dy * dy + dz * dz + dw * dw;
    }
    double local = (double)s * ((double)d2[i] + (double)d2[j]);
    #pragma unroll
    for (int off = 32; off > 0; off >>= 1) local += __shfl_down(local, off);
    __shared__ double wsum[4];
    if ((threadIdx.x & 63) == 0) wsum[threadIdx.x >> 6] = local;
    __syncthreads();
    if (threadIdx.x == 0)
        part[blockIdx.x] = wsum[0] + wsum[1] + wsum[2] + wsum[3];
}

__global__ __launch_bounds__(256) void reduce_part_k(
    const double* __restrict__ part, int n, float* __restrict__ out) {
    double s = 0.0;
    for (int i = threadIdx.x; i < n; i += 256) s += part[i];
    #pragma unroll
    for (int off = 32; off > 0; off >>= 1) s += __shfl_down(s, off);
    __shared__ double wsum[4];
    if ((threadIdx.x & 63) == 0) wsum[threadIdx.x >> 6] = s;
    __syncthreads();
    if (threadIdx.x == 0)
        out[0] = (float)((wsum[0] + wsum[1] + wsum[2] + wsum[3]) / (double)NPTS);
}

// ---------------------------------------------------------------------------
extern "C" void kernel_launch(void* const* d_in, const int* in_sizes, int n_in,
                              void* d_out, int out_size, void* d_ws, size_t ws_size,
                              hipStream_t stream) {
    const float* x1     = (const float*)d_in[0];
    const float* x2     = (const float*)d_in[1];
    const float* dists1 = (const float*)d_in[2];
    const int*   nn1    = (const int*)  d_in[3];
    const float* dists2 = (const float*)d_in[4];
    const int*   nn2    = (const int*)  d_in[5];
    const float* W1 = (const float*)d_in[6];  const float* b1 = (const float*)d_in[7];
    const float* W2 = (const float*)d_in[8];  const float* b2 = (const float*)d_in[9];
    const float* W3 = (const float*)d_in[10]; const float* b3 = (const float*)d_in[11];
    const float* W4 = (const float*)d_in[12]; const float* b4 = (const float*)d_in[13];

    char* ws = (char*)d_ws;
    size_t off = 0;
    auto alloc = [&](size_t bytes) { char* p = ws + off; off += (bytes + 255) & ~(size_t)255; return p; };
    u16*    xb   = (u16*)   alloc((size_t)NPTS * INDIM * 2);
    float*  yraw = (float*) alloc((size_t)NPTS * ODIM * 4);
    float*  yop  = (float*) alloc((size_t)NPTS * ODIM * 4);
    u16*    W1t  = (u16*)   alloc((size_t)HID * INDIM * 2);
    u16*    W2t  = (u16*)   alloc((size_t)HID * HID * 2);
    u16*    W3t  = (u16*)   alloc((size_t)HID2 * HID * 2);
    u16*    W4t  = (u16*)   alloc((size_t)ODIM * HID2 * 2);
    u16*    W4tP = (u16*)   alloc((size_t)ODIM * HID2 * 2);
    float*  b4f  = (float*) alloc(ODIM * 4);
    float*  d1   = (float*) alloc((size_t)NPTS * 4);
    float*  d2   = (float*) alloc((size_t)NPTS * 4);
    float*  wb1  = (float*) alloc((size_t)NPTS * KNN * 4);
    float*  wb2  = (float*) alloc((size_t)NPTS * KNN * 4);
    float*  dpart= (float*) alloc((size_t)2 * ESL * NPTS * 4);
    float*  gram = (float*) alloc(32 * 32 * 4);
    float*  oper = (float*) alloc(32 * 32 * 4);
    double* part = (double*)alloc((size_t)(NPTS * KNN / 256) * 8);
    size_t fixed = off;
    (void)in_sizes; (void)n_in; (void)out_size;

    // Chunk the MLP. Cap at 32768 rows: cb1+cb2 (134MB) + fixed buffers stay
    // L3-resident; cb buffers are REUSED across chunks.
    int chunk = 2048;
    for (int c = 32768; c >= 2048; c >>= 1)
        if (fixed + (size_t)c * 1024 * 2 * 2 + 512 <= ws_size) { chunk = c; break; }
    u16* cb1 = (u16*)alloc((size_t)chunk * HID * 2);
    u16* cb2 = (u16*)alloc((size_t)chunk * HID * 2);

    // weight transposes + zero-init
    trans_bf16_k<<<(INDIM * HID + 255) / 256, 256, 0, stream>>>(W1, W1t, INDIM, HID);
    trans_bf16_k<<<(HID * HID + 255) / 256, 256, 0, stream>>>(W2, W2t, HID, HID);
    trans_bf16_k<<<(HID * HID2 + 255) / 256, 256, 0, stream>>>(W3, W3t, HID, HID2);
    trans_bf16_k<<<(HID2 * ODIM + 255) / 256, 256, 0, stream>>>(W4, W4t, HID2, ODIM);
    hipMemsetAsync(gram, 0, 32 * 32 * 4, stream);

    // degree: 3-stage atomic-free
    edgew_k<<<dim3(NPTS / 256, 2), 256, 0, stream>>>(dists1, wb1, d1, dists2, wb2, d2);
    scatter_k<<<dim3(ESL, 4, 2), 512, 0, stream>>>(nn1, wb1, nn2, wb2, dpart);
    dreduce_k<<<dim3(NPTS / 256, 2), 256, 0, stream>>>(dpart, d1, d2);

    dim3 g12(HID / 256, chunk / 256);    // 4 x (chunk/256)
    dim3 g3(HID2 / 256, chunk / 256);    // 2 x (chunk/256)

    for (int pass = 0; pass < 2; ++pass) {
        const float* x = pass == 0 ? x1 : x2;
        cvt_bf16_k<<<(NPTS * INDIM / 4 + 255) / 256, 256, 0, stream>>>(x, xb, NPTS * INDIM / 4);
        for (int s0 = 0; s0 < NPTS; s0 += chunk) {
            const u16* Ain = xb + (size_t)s0 * INDIM;
            gemm256_k<true><<<g12, 512, 0, stream>>>(Ain, W1t, b1, cb1, chunk, HID, INDIM);
            gemm256_k<true><<<g12, 512, 0, stream>>>(cb1, W2t, b2, cb2, chunk, HID, HID);
            gemm256_k<true><<<g3, 512, 0, stream>>>(cb2, W3t, b3, cb1, chunk, HID2, HID);
            if (pass == 0)
                layer4_k<<<chunk / 64, 256, 0, stream>>>(
                    cb1, W4t, b4, d1 + s0, yraw + (size_t)s0 * ODIM, chunk);
            else
                layer4_k<<<chunk / 64, 256, 0, stream>>>(
                    cb1, W4tP, b4f, d2 + s0, yop + (size_t)s0 * ODIM, chunk);
        }
        if (pass == 0) {
            gram_k<<<256, 256, 0, stream>>>(yraw, gram);
            chol_oper_k<<<1, 256, 0, stream>>>(gram, oper);
            oper_fold_k<<<(HID2 * ODIM + ODIM + 255) / 256, 256, 0, stream>>>(
                W4, b4, oper, W4tP, b4f);
        } else {
            loss_k<<<NPTS * KNN / 256, 256, 0, stream>>>(yop, nn2, d2, part);
            reduce_part_k<<<1, 256, 0, stream>>>(part, NPTS * KNN / 256, (float*)d_out);
        }
    }
}